// Round 6
// baseline (104.900 us; speedup 1.0000x reference)
//
#include <hip/hip_runtime.h>
#include <hip/hip_bf16.h>

#define N 4096
#define D 512
#define MARGIN 0.5f
#define BETA 10.0f

typedef __attribute__((ext_vector_type(8))) short short8;
typedef __attribute__((ext_vector_type(4))) float floatx4;

__device__ inline unsigned short f2bf(float f) {
    unsigned u = __float_as_uint(f);
    u += 0x7fffu + ((u >> 16) & 1u);   // round-to-nearest-even
    return (unsigned short)(u >> 16);
}

#define GLOAD_LDS16(gp, lp)                                             \
    __builtin_amdgcn_global_load_lds(                                   \
        (const __attribute__((address_space(1))) void*)(gp),            \
        (__attribute__((address_space(3))) void*)(lp), 16, 0, 0)

// ---- Kernel 1: f32 -> bf16 convert + zero the accumulator buffers ----
__global__ __launch_bounds__(256) void convert_bf16_kernel(
        const float4* __restrict__ in, ushort4* __restrict__ out,
        float* __restrict__ sums /* 2*N floats to zero */) {
    int idx = blockIdx.x * 256 + threadIdx.x;
    if (idx < 2 * N) sums[idx] = 0.f;
    float4 v = in[idx];
    ushort4 o;
    o.x = f2bf(v.x); o.y = f2bf(v.y); o.z = f2bf(v.z); o.w = f2bf(v.w);
    out[idx] = o;
}

// ---- Kernel 2: fused sim-GEMM + masked exp sums, upper triangle ----
// OCCUPANCY-FIRST redesign after R3 (direct-global, latency-bound, 54us,
// Occ=16%) and R4 (BK=64 dbuf, 2 blocks/CU, 33us) both lost to plain R2
// (128-tile BK=32 2-barrier, 27us): intra-block pipelining can't hide the
// DMA drain at 2 blocks/CU. Fix via TLP: 64x64 tiles -> 2080 triangle
// blocks (~8/CU), 32.5 KB LDS, light registers -> 4+ blocks (16+ waves)
// resident per CU; one block's staging overlaps others' compute (m114).
// BK=128 -> only 4 K-iters, 8 barriers/block total. Proven 16x16x32
// fragment layouts and 2-barrier loop shape retained from R2.
__global__ __launch_bounds__(256, 4) void ms_loss_gemm(
        const unsigned short* __restrict__ Ebf,
        const int* __restrict__ labels,
        float* __restrict__ pos_sum,
        float* __restrict__ neg_sum) {
    __shared__ char Als[64 * 256];   // 16 KB: 64 rows x 256 B (BK=128)
    __shared__ char Bls[64 * 256];   // 16 KB
    __shared__ int rlab[64];
    __shared__ int clab[64];

    // decode linear block id -> upper-triangle tile (bi, bj), bi <= bj
    int t = blockIdx.x;
    int bi = 0;
    while (t >= (64 - bi)) { t -= (64 - bi); ++bi; }
    const int bj = bi + t;
    const bool diag = (bi == bj);

    const int tid  = threadIdx.x;
    const int wave = tid >> 6;
    const int lane = tid & 63;
    const int quad = lane >> 4;      // 0..3
    const int lcol = lane & 15;      // 0..15
    const int wrow = wave >> 1;      // 0..1  (32-row half)
    const int wcol = wave & 1;       // 0..1  (32-col half)
    const int ibase = bi * 64;
    const int jbase = bj * 64;

    if (tid < 64)        rlab[tid]      = labels[ibase + tid];
    else if (tid < 128)  clab[tid - 64] = labels[jbase + tid - 64];

    floatx4 acc[2][2];
#pragma unroll
    for (int mt = 0; mt < 2; ++mt)
#pragma unroll
        for (int nt = 0; nt < 2; ++nt)
            acc[mt][nt] = (floatx4){0.f, 0.f, 0.f, 0.f};

    const char* Eb = (const char*)Ebf;                 // row stride 1024 B
    // Staging: tile row = it*16 + wave*4 + srow, 16 B chunk slot = lane&15.
    // XOR swizzle on the GLOBAL chunk (dest must stay lane-contiguous):
    // LDS slot c of row r holds global chunk c ^ (r & 15).
    const int srow = lane >> 4;                        // 0..3
    const int sgrp = wave * 4 + srow;                  // row & 15
    const int sck  = ((lane & 15) ^ sgrp) * 16;        // swizzled global chunk
    const size_t aoff0 = (size_t)(ibase + sgrp) * 1024 + sck;
    const size_t boff0 = (size_t)(jbase + sgrp) * 1024 + sck;
    const int ldso = wave * 1024 + lane * 16;          // + it*4096

#define STAGE(kt_)                                                         \
    {                                                                      \
        const int kb_ = (kt_) * 256;                                       \
        _Pragma("unroll")                                                  \
        for (int it = 0; it < 4; ++it) {                                   \
            GLOAD_LDS16(Eb + aoff0 + (size_t)it * 16384 + kb_,             \
                        Als + ldso + it * 4096);                           \
            if (!diag)                                                     \
                GLOAD_LDS16(Eb + boff0 + (size_t)it * 16384 + kb_,         \
                            Bls + ldso + it * 4096);                       \
        }                                                                  \
    }

#pragma unroll
    for (int kt = 0; kt < D / 128; ++kt) {
        __syncthreads();            // prev reads done (and labels, kt=0)
        STAGE(kt);
        __syncthreads();            // compiler drains vmcnt(0) here: DMA landed

        const char* Ac = Als;
        const char* Bc = diag ? Als : Bls;
#pragma unroll
        for (int s = 0; s < 4; ++s) {
            short8 a[2], b[2];
            // frag row r has r&15 == lcol; want global chunk s*4+quad
            const int rslot = ((s * 4 + quad) ^ lcol) * 16;
#pragma unroll
            for (int mt = 0; mt < 2; ++mt) {
                int r = wrow * 32 + mt * 16 + lcol;
                a[mt] = *(const short8*)(Ac + r * 256 + rslot);
            }
#pragma unroll
            for (int nt = 0; nt < 2; ++nt) {
                int c = wcol * 32 + nt * 16 + lcol;
                b[nt] = *(const short8*)(Bc + c * 256 + rslot);
            }
#pragma unroll
            for (int mt = 0; mt < 2; ++mt)
#pragma unroll
                for (int nt = 0; nt < 2; ++nt)
                    acc[mt][nt] = __builtin_amdgcn_mfma_f32_16x16x32_bf16(
                        a[mt], b[nt], acc[mt][nt], 0, 0, 0);
        }
    }

    // ---- epilogue ----
    // C layout (m89-verified): col = lane&15, row = quad*4 + reg
    int ljv[2], gjv[2];
#pragma unroll
    for (int nt = 0; nt < 2; ++nt) {
        int cl = wcol * 32 + nt * 16 + lcol;
        ljv[nt] = clab[cl];
        gjv[nt] = jbase + cl;
    }

    float colp[2] = {0.f, 0.f};
    float coln[2] = {0.f, 0.f};

#pragma unroll
    for (int mt = 0; mt < 2; ++mt) {
#pragma unroll
        for (int reg = 0; reg < 4; ++reg) {
            int rl = wrow * 32 + mt * 16 + quad * 4 + reg;
            int gi = ibase + rl;
            int li = rlab[rl];
            float p = 0.f, ng = 0.f;
#pragma unroll
            for (int nt = 0; nt < 2; ++nt) {
                float s = acc[mt][nt][reg];
                if (gi != gjv[nt]) {
                    if (li == ljv[nt]) {
                        float e = __expf(MARGIN - s);          // alpha = 1
                        p += e;  colp[nt] += e;
                    } else {
                        float e = __expf(BETA * (s - MARGIN));
                        ng += e; coln[nt] += e;
                    }
                }
            }
            // row-sum: reduce across the 16 lcol lanes (distinct cols)
            p  += __shfl_xor(p, 1);   ng += __shfl_xor(ng, 1);
            p  += __shfl_xor(p, 2);   ng += __shfl_xor(ng, 2);
            p  += __shfl_xor(p, 4);   ng += __shfl_xor(ng, 4);
            p  += __shfl_xor(p, 8);   ng += __shfl_xor(ng, 8);
            if (lcol == 0) {
                atomicAdd(&pos_sum[gi], p);
                atomicAdd(&neg_sum[gi], ng);
            }
        }
    }

    // col-sum (mirror credit), off-diagonal blocks only: reduce over quads
    if (!diag) {
#pragma unroll
        for (int nt = 0; nt < 2; ++nt) {
            float cp = colp[nt], cn = coln[nt];
            cp += __shfl_xor(cp, 16);  cn += __shfl_xor(cn, 16);
            cp += __shfl_xor(cp, 32);  cn += __shfl_xor(cn, 32);
            if (quad == 0) {
                int gj = gjv[nt];
                atomicAdd(&pos_sum[gj], cp);
                atomicAdd(&neg_sum[gj], cn);
            }
        }
    }
}

// ---- Kernel 3: finalize ----
__global__ __launch_bounds__(256) void finalize_kernel(
        const float4* __restrict__ pos4, const float4* __restrict__ neg4,
        float* __restrict__ out) {
    __shared__ float sb[256];
    __shared__ int   sc[256];
    const int tid = threadIdx.x;
    float tot = 0.f;
    int cnt = 0;
#pragma unroll
    for (int it = 0; it < N / 4 / 256; ++it) {
        int i = it * 256 + tid;
        float4 p = pos4[i];
        float4 ng = neg4[i];
        const float* pp = (const float*)&p;
        const float* nn = (const float*)&ng;
#pragma unroll
        for (int j = 0; j < 4; ++j) {
            if (pp[j] > 0.f && nn[j] > 0.f) {
                tot += log1pf(pp[j]) + (1.0f / BETA) * log1pf(nn[j]);
                cnt += 1;
            }
        }
    }
    sb[tid] = tot; sc[tid] = cnt;
    __syncthreads();
    for (int s = 128; s > 0; s >>= 1) {
        if (tid < s) { sb[tid] += sb[tid + s]; sc[tid] += sc[tid + s]; }
        __syncthreads();
    }
    if (tid == 0) out[0] = (sc[0] > 0) ? sb[0] / (float)sc[0] : 0.f;
}

extern "C" void kernel_launch(void* const* d_in, const int* in_sizes, int n_in,
                              void* d_out, int out_size, void* d_ws, size_t ws_size,
                              hipStream_t stream) {
    const float* emb   = (const float*)d_in[0];
    const int* labels  = (const int*)d_in[1];
    float* out         = (float*)d_out;

    char* ws = (char*)d_ws;
    unsigned short* Ebf = (unsigned short*)ws;                 // 4 MB
    float* pos_sum = (float*)(ws + (size_t)N * D * 2);         // 16 KB
    float* neg_sum = pos_sum + N;                              // 16 KB

    convert_bf16_kernel<<<(N * D / 4) / 256, 256, 0, stream>>>(
        (const float4*)emb, (ushort4*)Ebf, pos_sum);

    ms_loss_gemm<<<(64 * 65) / 2, 256, 0, stream>>>(Ebf, labels, pos_sum, neg_sum);

    finalize_kernel<<<1, 256, 0, stream>>>(
        (const float4*)pos_sum, (const float4*)neg_sum, out);
}

// Round 7
// 101.200 us; speedup vs baseline: 1.0366x; 1.0366x over previous
//
#include <hip/hip_runtime.h>
#include <hip/hip_bf16.h>

#define N 4096
#define D 512
#define MARGIN 0.5f
#define BETA 10.0f

typedef __attribute__((ext_vector_type(8))) short short8;
typedef __attribute__((ext_vector_type(4))) float floatx4;

__device__ inline unsigned short f2bf(float f) {
    unsigned u = __float_as_uint(f);
    u += 0x7fffu + ((u >> 16) & 1u);   // round-to-nearest-even
    return (unsigned short)(u >> 16);
}

#define GLOAD_LDS16(gp, lp)                                             \
    __builtin_amdgcn_global_load_lds(                                   \
        (const __attribute__((address_space(1))) void*)(gp),            \
        (__attribute__((address_space(3))) void*)(lp), 16, 0, 0)

// ---- Kernel 1: f32 -> bf16 convert + zero the accumulator buffers ----
__global__ __launch_bounds__(256) void convert_bf16_kernel(
        const float4* __restrict__ in, ushort4* __restrict__ out,
        float* __restrict__ sums /* 2*N floats to zero */) {
    int idx = blockIdx.x * 256 + threadIdx.x;
    if (idx < 2 * N) sums[idx] = 0.f;
    float4 v = in[idx];
    ushort4 o;
    o.x = f2bf(v.x); o.y = f2bf(v.y); o.z = f2bf(v.z); o.w = f2bf(v.w);
    out[idx] = o;
}

// ---- Kernel 2: fused sim-GEMM + masked exp sums ----
// Evidence R1-R5: 128-row tiles are the efficient shape (R2, 27us GEMM),
// but the 528-block triangle grid gives only 2.06 blocks/CU and the
// serial stage->drain cadence has nothing to overlap with (R1 at 4
// blocks/CU had 1.58x better per-block time). Pipelining (R3/R4) and
// small tiles (R5) both regressed. This version keeps the triangle FLOP
// savings AND restores residency: each 128x128 triangle tile is split
// into two 128x64 j-halves -> 1056 blocks (~4.1/CU, launch_bounds(256,4),
// 24.8 KB LDS, acc only 32 VGPRs). One block's DMA drain overlaps three
// other blocks' compute (m114). BK=64 single buffer: 8 K-iters, 16
// barriers total (vs R2's 32). Mirror credit: off-diag blocks credit
// their 128 rows AND their 64 cols with the same exp values.
__global__ __launch_bounds__(256, 4) void ms_loss_gemm(
        const unsigned short* __restrict__ Ebf,
        const int* __restrict__ labels,
        float* __restrict__ pos_sum,
        float* __restrict__ neg_sum) {
    __shared__ char Als[128 * 128];   // 16 KB: 128 rows x 128 B (BK=64)
    __shared__ char Bls[64 * 128];    //  8 KB:  64 rows x 128 B
    __shared__ int rlab[128];
    __shared__ int clab[64];

    // decode block id -> (upper-triangle pair, j-half)
    int t = blockIdx.x;
    const int h = t & 1;
    int pr = t >> 1;
    int bi = 0;
    while (pr >= (32 - bi)) { pr -= (32 - bi); ++bi; }
    const int bj = bi + pr;
    const bool diag = (bi == bj);     // no mirror credit (other half covers it)

    const int tid  = threadIdx.x;
    const int wave = tid >> 6;
    const int lane = tid & 63;
    const int quad = lane >> 4;      // 0..3
    const int lcol = lane & 15;      // 0..15
    const int wrow = wave >> 1;      // 0..1  (64-row half)
    const int wcol = wave & 1;       // 0..1  (32-col half)
    const int ibase = bi * 128;
    const int jbase = bj * 128 + h * 64;

    if (tid < 128)       rlab[tid]       = labels[ibase + tid];
    else if (tid < 192)  clab[tid - 128] = labels[jbase + tid - 128];

    floatx4 acc[4][2];
#pragma unroll
    for (int mt = 0; mt < 4; ++mt)
#pragma unroll
        for (int nt = 0; nt < 2; ++nt)
            acc[mt][nt] = (floatx4){0.f, 0.f, 0.f, 0.f};

    const char* Eb = (const char*)Ebf;                 // row stride 1024 B
    // Staging (BK=64): DMA instr = 8 rows x 128 B. XOR swizzle on the
    // GLOBAL chunk (dest must stay lane-contiguous): LDS slot c of row r
    // holds global chunk c ^ (r&7).
    const int srow8 = lane >> 3;                       // 0..7
    const int sck   = ((lane & 7) ^ srow8) * 16;       // swizzled chunk
    const size_t aoff0 = (size_t)(ibase + wave * 8 + srow8) * 1024 + sck;
    const size_t boff0 = (size_t)(jbase + wave * 8 + srow8) * 1024 + sck;
    const int ldso = wave * 1024 + lane * 16;          // + it*4096

#define STAGE(kt_)                                                         \
    {                                                                      \
        const int kb_ = (kt_) * 128;                                       \
        _Pragma("unroll")                                                  \
        for (int it = 0; it < 4; ++it)                                     \
            GLOAD_LDS16(Eb + aoff0 + (size_t)it * 32768 + kb_,             \
                        Als + ldso + it * 4096);                           \
        _Pragma("unroll")                                                  \
        for (int it = 0; it < 2; ++it)                                     \
            GLOAD_LDS16(Eb + boff0 + (size_t)it * 32768 + kb_,             \
                        Bls + ldso + it * 4096);                           \
    }

    const int rsw = lcol & 7;        // frag row r has r&7 == lcol&7

#pragma unroll
    for (int kt = 0; kt < D / 64; ++kt) {
        __syncthreads();             // prev reads done (and labels, kt=0)
        STAGE(kt);
        __syncthreads();             // vmcnt(0) drain: DMA landed

#pragma unroll
        for (int s = 0; s < 2; ++s) {
            short8 a[4], b[2];
            const int rslot = ((s * 4 + quad) ^ rsw) * 16;
#pragma unroll
            for (int mt = 0; mt < 4; ++mt) {
                int r = wrow * 64 + mt * 16 + lcol;
                a[mt] = *(const short8*)(Als + r * 128 + rslot);
            }
#pragma unroll
            for (int nt = 0; nt < 2; ++nt) {
                int c = wcol * 32 + nt * 16 + lcol;
                b[nt] = *(const short8*)(Bls + c * 128 + rslot);
            }
#pragma unroll
            for (int mt = 0; mt < 4; ++mt)
#pragma unroll
                for (int nt = 0; nt < 2; ++nt)
                    acc[mt][nt] = __builtin_amdgcn_mfma_f32_16x16x32_bf16(
                        a[mt], b[nt], acc[mt][nt], 0, 0, 0);
        }
    }

    // ---- epilogue ----
    // C layout (m89-verified): col = lane&15, row = quad*4 + reg
    int ljv[2], gjv[2];
#pragma unroll
    for (int nt = 0; nt < 2; ++nt) {
        int cl = wcol * 32 + nt * 16 + lcol;
        ljv[nt] = clab[cl];
        gjv[nt] = jbase + cl;
    }

    float colp[2] = {0.f, 0.f};
    float coln[2] = {0.f, 0.f};

#pragma unroll
    for (int mt = 0; mt < 4; ++mt) {
#pragma unroll
        for (int reg = 0; reg < 4; ++reg) {
            int rl = wrow * 64 + mt * 16 + quad * 4 + reg;
            int gi = ibase + rl;
            int li = rlab[rl];
            float p = 0.f, ng = 0.f;
#pragma unroll
            for (int nt = 0; nt < 2; ++nt) {
                float s = acc[mt][nt][reg];
                if (gi != gjv[nt]) {
                    if (li == ljv[nt]) {
                        float e = __expf(MARGIN - s);          // alpha = 1
                        p += e;  colp[nt] += e;
                    } else {
                        float e = __expf(BETA * (s - MARGIN));
                        ng += e; coln[nt] += e;
                    }
                }
            }
            // row-sum: reduce across the 16 lcol lanes (distinct cols)
            p  += __shfl_xor(p, 1);   ng += __shfl_xor(ng, 1);
            p  += __shfl_xor(p, 2);   ng += __shfl_xor(ng, 2);
            p  += __shfl_xor(p, 4);   ng += __shfl_xor(ng, 4);
            p  += __shfl_xor(p, 8);   ng += __shfl_xor(ng, 8);
            if (lcol == 0) {
                atomicAdd(&pos_sum[gi], p);
                atomicAdd(&neg_sum[gi], ng);
            }
        }
    }

    // col-sum (mirror credit), off-diagonal tile-pairs only
    if (!diag) {
#pragma unroll
        for (int nt = 0; nt < 2; ++nt) {
            float cp = colp[nt], cn = coln[nt];
            cp += __shfl_xor(cp, 16);  cn += __shfl_xor(cn, 16);
            cp += __shfl_xor(cp, 32);  cn += __shfl_xor(cn, 32);
            if (quad == 0) {
                int gj = gjv[nt];
                atomicAdd(&pos_sum[gj], cp);
                atomicAdd(&neg_sum[gj], cn);
            }
        }
    }
}

// ---- Kernel 3: finalize ----
__global__ __launch_bounds__(256) void finalize_kernel(
        const float4* __restrict__ pos4, const float4* __restrict__ neg4,
        float* __restrict__ out) {
    __shared__ float sb[256];
    __shared__ int   sc[256];
    const int tid = threadIdx.x;
    float tot = 0.f;
    int cnt = 0;
#pragma unroll
    for (int it = 0; it < N / 4 / 256; ++it) {
        int i = it * 256 + tid;
        float4 p = pos4[i];
        float4 ng = neg4[i];
        const float* pp = (const float*)&p;
        const float* nn = (const float*)&ng;
#pragma unroll
        for (int j = 0; j < 4; ++j) {
            if (pp[j] > 0.f && nn[j] > 0.f) {
                tot += log1pf(pp[j]) + (1.0f / BETA) * log1pf(nn[j]);
                cnt += 1;
            }
        }
    }
    sb[tid] = tot; sc[tid] = cnt;
    __syncthreads();
    for (int s = 128; s > 0; s >>= 1) {
        if (tid < s) { sb[tid] += sb[tid + s]; sc[tid] += sc[tid + s]; }
        __syncthreads();
    }
    if (tid == 0) out[0] = (sc[0] > 0) ? sb[0] / (float)sc[0] : 0.f;
}

extern "C" void kernel_launch(void* const* d_in, const int* in_sizes, int n_in,
                              void* d_out, int out_size, void* d_ws, size_t ws_size,
                              hipStream_t stream) {
    const float* emb   = (const float*)d_in[0];
    const int* labels  = (const int*)d_in[1];
    float* out         = (float*)d_out;

    char* ws = (char*)d_ws;
    unsigned short* Ebf = (unsigned short*)ws;                 // 4 MB
    float* pos_sum = (float*)(ws + (size_t)N * D * 2);         // 16 KB
    float* neg_sum = pos_sum + N;                              // 16 KB

    convert_bf16_kernel<<<(N * D / 4) / 256, 256, 0, stream>>>(
        (const float4*)emb, (ushort4*)Ebf, pos_sum);

    ms_loss_gemm<<<(32 * 33) / 2 * 2, 256, 0, stream>>>(
        Ebf, labels, pos_sum, neg_sum);

    finalize_kernel<<<1, 256, 0, stream>>>(
        (const float4*)pos_sum, (const float4*)neg_sum, out);
}

// Round 8
// 95.275 us; speedup vs baseline: 1.1010x; 1.0622x over previous
//
#include <hip/hip_runtime.h>
#include <hip/hip_bf16.h>

#define N 4096
#define D 512
#define MARGIN 0.5f
#define BETA 10.0f

typedef __attribute__((ext_vector_type(8))) short short8;
typedef __attribute__((ext_vector_type(4))) float floatx4;

__device__ inline unsigned short f2bf(float f) {
    unsigned u = __float_as_uint(f);
    u += 0x7fffu + ((u >> 16) & 1u);   // round-to-nearest-even
    return (unsigned short)(u >> 16);
}

// ---- Kernel 1: f32 -> bf16 convert + zero the accumulator buffers ----
__global__ __launch_bounds__(256) void convert_bf16_kernel(
        const float4* __restrict__ in, ushort4* __restrict__ out,
        float* __restrict__ sums /* 2*N floats to zero */) {
    int idx = blockIdx.x * 256 + threadIdx.x;
    if (idx < 2 * N) sums[idx] = 0.f;
    float4 v = in[idx];
    ushort4 o;
    o.x = f2bf(v.x); o.y = f2bf(v.y); o.z = f2bf(v.z); o.w = f2bf(v.w);
    out[idx] = o;
}

// ---- Kernel 2: fused sim-GEMM + masked exp sums, upper triangle ----
// R2's shape (128x128 tile, BK=32, 528 triangle blocks — best measured,
// 27us GEMM) with ONE change: staging via global_load->VGPR->ds_write
// instead of global_load_lds DMA. Rationale (R1-R6 post-mortems): the DMA
// path forces the compiler to emit s_waitcnt vmcnt(0) before s_barrier
// (LDS is the DMA target, shared), serializing [issue -> full-latency
// drain -> 80cyc MFMA] every kt at ~2 blocks/CU. Register loads are
// thread-private: barriers drain only lgkmcnt (~tens of cycles), and the
// kt+1 prefetch's latency hides behind kt's MFMA phase, waited at the
// next ds_write. LDS layout, swizzle, fragment reads, epilogue identical
// to R2 (verified).
__global__ __launch_bounds__(256, 2) void ms_loss_gemm(
        const unsigned short* __restrict__ Ebf,
        const int* __restrict__ labels,
        float* __restrict__ pos_sum,
        float* __restrict__ neg_sum) {
    __shared__ char Als[128 * 64];   // 8 KB: 128 rows x 64 B (BK=32)
    __shared__ char Bls[128 * 64];   // 8 KB
    __shared__ int rlab[128];
    __shared__ int clab[128];

    // decode linear block id -> upper-triangle tile (bi, bj), bi <= bj
    int t = blockIdx.x;
    int bi = 0;
    while (t >= (32 - bi)) { t -= (32 - bi); ++bi; }
    const int bj = bi + t;
    const bool diag = (bi == bj);

    const int tid  = threadIdx.x;
    const int wave = tid >> 6;
    const int lane = tid & 63;
    const int quad = lane >> 4;      // 0..3
    const int lcol = lane & 15;      // 0..15
    const int wrow = wave >> 1;      // 0..1
    const int wcol = wave & 1;       // 0..1
    const int ibase = bi * 128;
    const int jbase = bj * 128;

    if (tid < 128)       rlab[tid]       = labels[ibase + tid];
    else                 clab[tid - 128] = labels[jbase + tid - 128];

    floatx4 acc[4][4];
#pragma unroll
    for (int mt = 0; mt < 4; ++mt)
#pragma unroll
        for (int nt = 0; nt < 4; ++nt)
            acc[mt][nt] = (floatx4){0.f, 0.f, 0.f, 0.f};

    const char* Eb = (const char*)Ebf;                 // row stride 1024 B
    // Staging geometry: lane covers (row = it*64 + wave*16 + (lane>>2),
    // chunk = lane&3) for it in {0,1}; global reads are coalesced 64 B
    // row-segments; the XOR swizzle goes on the ds_write address (free to
    // scatter now — no DMA lane-contiguity constraint):
    // LDS slot for (row, chunk c) = row*64 + (c ^ ((row>>1)&3))*16.
    const int srow  = wave * 16 + (lane >> 2);         // 0..63 (it adds 64)
    const int schunk = lane & 3;
    const int swz   = (lane >> 3) & 3;                 // ((row>>1)&3), it-invariant
    const int ldw   = srow * 64 + (schunk ^ swz) * 16; // + it*4096
    const size_t ga0 = (size_t)(ibase + srow) * 1024 + schunk * 16;
    const size_t gb0 = (size_t)(jbase + srow) * 1024 + schunk * 16;

    const int rdsw = (lcol >> 1) & 3;                  // read-side XOR term
    const char* Bread = diag ? Als : Bls;

    short8 pa[2], pb[2];
#pragma unroll
    for (int it = 0; it < 2; ++it) {
        pa[it] = *(const short8*)(Eb + ga0 + (size_t)it * 65536);
        if (!diag) pb[it] = *(const short8*)(Eb + gb0 + (size_t)it * 65536);
    }

    for (int kt = 0; kt < D / 32; ++kt) {
        __syncthreads();             // prev ds_reads done (lgkm-only drain)
#pragma unroll
        for (int it = 0; it < 2; ++it) {
            *(short8*)(Als + ldw + it * 4096) = pa[it];
            if (!diag) *(short8*)(Bls + ldw + it * 4096) = pb[it];
        }
        if (kt < D / 32 - 1) {
            const size_t kb = (size_t)(kt + 1) * 64;
#pragma unroll
            for (int it = 0; it < 2; ++it) {
                pa[it] = *(const short8*)(Eb + ga0 + (size_t)it * 65536 + kb);
                if (!diag)
                    pb[it] = *(const short8*)(Eb + gb0 + (size_t)it * 65536 + kb);
            }
        }
        __syncthreads();             // writes visible (lgkm-only drain)

        short8 a[4], b[4];
        const int rchunk = (quad ^ rdsw) * 16;
#pragma unroll
        for (int mt = 0; mt < 4; ++mt) {
            int r = wrow * 64 + mt * 16 + lcol;
            a[mt] = *(const short8*)(Als + r * 64 + rchunk);
        }
#pragma unroll
        for (int nt = 0; nt < 4; ++nt) {
            int c = wcol * 64 + nt * 16 + lcol;
            b[nt] = *(const short8*)(Bread + c * 64 + rchunk);
        }
#pragma unroll
        for (int mt = 0; mt < 4; ++mt)
#pragma unroll
            for (int nt = 0; nt < 4; ++nt)
                acc[mt][nt] = __builtin_amdgcn_mfma_f32_16x16x32_bf16(
                    a[mt], b[nt], acc[mt][nt], 0, 0, 0);
    }

    // ---- epilogue ----
    // C layout (m89-verified): col = lane&15, row = quad*4 + reg
    int ljv[4], gjv[4];
#pragma unroll
    for (int nt = 0; nt < 4; ++nt) {
        int cl = wcol * 64 + nt * 16 + lcol;
        ljv[nt] = clab[cl];
        gjv[nt] = jbase + cl;
    }

    float colp[4] = {0.f, 0.f, 0.f, 0.f};
    float coln[4] = {0.f, 0.f, 0.f, 0.f};

#pragma unroll
    for (int mt = 0; mt < 4; ++mt) {
#pragma unroll
        for (int reg = 0; reg < 4; ++reg) {
            int rl = wrow * 64 + mt * 16 + quad * 4 + reg;
            int gi = ibase + rl;
            int li = rlab[rl];
            float p = 0.f, ng = 0.f;
#pragma unroll
            for (int nt = 0; nt < 4; ++nt) {
                float s = acc[mt][nt][reg];
                if (gi != gjv[nt]) {
                    if (li == ljv[nt]) {
                        float e = __expf(MARGIN - s);          // alpha = 1
                        p += e;  colp[nt] += e;
                    } else {
                        float e = __expf(BETA * (s - MARGIN));
                        ng += e; coln[nt] += e;
                    }
                }
            }
            // row-sum: reduce across the 16 lcol lanes (distinct cols)
            p  += __shfl_xor(p, 1);   ng += __shfl_xor(ng, 1);
            p  += __shfl_xor(p, 2);   ng += __shfl_xor(ng, 2);
            p  += __shfl_xor(p, 4);   ng += __shfl_xor(ng, 4);
            p  += __shfl_xor(p, 8);   ng += __shfl_xor(ng, 8);
            if (lcol == 0) {
                atomicAdd(&pos_sum[gi], p);
                atomicAdd(&neg_sum[gi], ng);
            }
        }
    }

    // col-sum (mirror credit), off-diagonal blocks only
    if (!diag) {
#pragma unroll
        for (int nt = 0; nt < 4; ++nt) {
            float cp = colp[nt], cn = coln[nt];
            cp += __shfl_xor(cp, 16);  cn += __shfl_xor(cn, 16);
            cp += __shfl_xor(cp, 32);  cn += __shfl_xor(cn, 32);
            if (quad == 0) {
                int gj = gjv[nt];
                atomicAdd(&pos_sum[gj], cp);
                atomicAdd(&neg_sum[gj], cn);
            }
        }
    }
}

// ---- Kernel 3: finalize ----
__global__ __launch_bounds__(256) void finalize_kernel(
        const float4* __restrict__ pos4, const float4* __restrict__ neg4,
        float* __restrict__ out) {
    __shared__ float sb[256];
    __shared__ int   sc[256];
    const int tid = threadIdx.x;
    float tot = 0.f;
    int cnt = 0;
#pragma unroll
    for (int it = 0; it < N / 4 / 256; ++it) {
        int i = it * 256 + tid;
        float4 p = pos4[i];
        float4 ng = neg4[i];
        const float* pp = (const float*)&p;
        const float* nn = (const float*)&ng;
#pragma unroll
        for (int j = 0; j < 4; ++j) {
            if (pp[j] > 0.f && nn[j] > 0.f) {
                tot += log1pf(pp[j]) + (1.0f / BETA) * log1pf(nn[j]);
                cnt += 1;
            }
        }
    }
    sb[tid] = tot; sc[tid] = cnt;
    __syncthreads();
    for (int s = 128; s > 0; s >>= 1) {
        if (tid < s) { sb[tid] += sb[tid + s]; sc[tid] += sc[tid + s]; }
        __syncthreads();
    }
    if (tid == 0) out[0] = (sc[0] > 0) ? sb[0] / (float)sc[0] : 0.f;
}

extern "C" void kernel_launch(void* const* d_in, const int* in_sizes, int n_in,
                              void* d_out, int out_size, void* d_ws, size_t ws_size,
                              hipStream_t stream) {
    const float* emb   = (const float*)d_in[0];
    const int* labels  = (const int*)d_in[1];
    float* out         = (float*)d_out;

    char* ws = (char*)d_ws;
    unsigned short* Ebf = (unsigned short*)ws;                 // 4 MB
    float* pos_sum = (float*)(ws + (size_t)N * D * 2);         // 16 KB
    float* neg_sum = pos_sum + N;                              // 16 KB

    convert_bf16_kernel<<<(N * D / 4) / 256, 256, 0, stream>>>(
        (const float4*)emb, (ushort4*)Ebf, pos_sum);

    ms_loss_gemm<<<(32 * 33) / 2, 256, 0, stream>>>(Ebf, labels, pos_sum, neg_sum);

    finalize_kernel<<<1, 256, 0, stream>>>(
        (const float4*)pos_sum, (const float4*)neg_sum, out);
}